// Round 5
// baseline (197.096 us; speedup 1.0000x reference)
//
#include <hip/hip_runtime.h>

#define N_PTS  20000
#define Q      8                    // queries per thread (named-scalar chains)
#define QPB    (256 * Q)            // 2048 queries per block
#define NQB    ((N_PTS + QPB - 1) / QPB)       // 10
#define NSEG   64                   // ref segments
#define SEGLEN ((N_PTS + NSEG - 1) / NSEG)     // 313 (last seg = 281)
#define QB79   79                   // fallback kernel

// ---- numpy-exact arithmetic (no FMA, no reassociation) ----
__device__ __forceinline__ float np_self_dot(float x, float y, float z) {
    return __fadd_rn(__fadd_rn(__fmul_rn(x, x), __fmul_rn(y, y)),
                     __fmul_rn(z, z));
}

// monotone float->u32 map (ascending bits == ascending float)
__device__ __forceinline__ unsigned int ordmap(float f) {
    unsigned int b = __float_as_uint(f);
    return (b & 0x80000000u) ? ~b : (b | 0x80000000u);
}

// Pack both clouds as (x, y, z, selfdot) float4 and init atomic keys.
__global__ __launch_bounds__(256) void chamfer_prep(
    const float* __restrict__ preds, const float* __restrict__ gts,
    float4* __restrict__ packed,                 // [2*N_PTS]
    unsigned long long* __restrict__ keys)       // [2*N_PTS]
{
    int t = blockIdx.x * 256 + threadIdx.x;
    if (t >= 2 * N_PTS) return;
    const float* src = (t < N_PTS) ? preds : gts;
    int i = (t < N_PTS) ? t : t - N_PTS;
    float x = src[i * 3 + 0], y = src[i * 3 + 1], z = src[i * 3 + 2];
    packed[t] = make_float4(x, y, z, np_self_dot(x, y, z));
    keys[t] = ~0ULL;
}

// Main kernel: no LDS. Refs read at wave-uniform addresses (scalar/uniform
// loads); queries register-resident with coords pre-doubled (exact x2):
//   d = fl( fl(sq+sr) - fl( fl(fl(2qx*rx)+fl(2qy*ry)) + fl(2qz*rz) ) )
// == numpy's fl(fl(xx+yy) - 2*zz) bit-exactly (x2 commutes with RN rounding).
// Partials merged via u64 atomicMin of (ordmap(d)<<32 | idx): min key ==
// (min dist, then min idx) == numpy first-occurrence argmin. Deterministic.
__global__ __launch_bounds__(256, 4) void chamfer_main(
    const float4* __restrict__ packed,
    unsigned long long* __restrict__ keys)
{
    int bid = blockIdx.x;
    int dir = bid / (NQB * NSEG);
    int rem = bid - dir * (NQB * NSEG);
    int seg = rem / NQB;
    int qb  = rem - seg * NQB;

    const float4* qarr = packed + (dir == 0 ? 0 : N_PTS);
    const float4* rarr = packed + (dir == 0 ? N_PTS : 0);

    int qbase = qb * QPB + threadIdx.x;

    // ---- 8 query chains in named scalars, coords doubled at load
#define LOADQ(n)                                                          \
    float qx##n, qy##n, qz##n, sq##n, best##n; int bidx##n;               \
    {   int q  = qbase + n * 256;                                         \
        int qc = (q < N_PTS) ? q : (N_PTS - 1);                           \
        float4 v = qarr[qc];                                              \
        qx##n = v.x + v.x; qy##n = v.y + v.y; qz##n = v.z + v.z;          \
        sq##n = v.w; best##n = 3.4e38f; bidx##n = 0; }
    LOADQ(0) LOADQ(1) LOADQ(2) LOADQ(3) LOADQ(4) LOADQ(5) LOADQ(6) LOADQ(7)
#undef LOADQ

    int s0  = seg * SEGLEN;
    int len = min(SEGLEN, N_PTS - s0);

#define CHAIN(n)                                                          \
    {   float d = __fsub_rn(__fadd_rn(sq##n, rw),                         \
            __fadd_rn(__fadd_rn(__fmul_rn(qx##n, rx), __fmul_rn(qy##n, ry)), \
                      __fmul_rn(qz##n, rz)));                             \
        bool lt = d < best##n;                                            \
        best##n = lt ? d : best##n;                                       \
        bidx##n = lt ? kk : bidx##n; }

    #pragma unroll 4
    for (int k = 0; k < len; ++k) {
        float4 r = rarr[s0 + k];        // wave-uniform -> scalar/uniform load
        float rx = r.x, ry = r.y, rz = r.z, rw = r.w;
        int   kk = s0 + k;
        CHAIN(0) CHAIN(1) CHAIN(2) CHAIN(3)
        CHAIN(4) CHAIN(5) CHAIN(6) CHAIN(7)
    }
#undef CHAIN

#define EMIT(n)                                                           \
    {   int q = qbase + n * 256;                                          \
        if (q < N_PTS) {                                                  \
            unsigned long long key =                                      \
                ((unsigned long long)ordmap(best##n) << 32) |             \
                (unsigned int)bidx##n;                                    \
            atomicMin(&keys[dir * N_PTS + q], key);                       \
        } }
    EMIT(0) EMIT(1) EMIT(2) EMIT(3) EMIT(4) EMIT(5) EMIT(6) EMIT(7)
#undef EMIT
}

__global__ __launch_bounds__(256) void chamfer_finalize(
    const unsigned long long* __restrict__ keys,
    float* __restrict__ out)
{
    int t = blockIdx.x * 256 + threadIdx.x;
    if (t >= 2 * N_PTS) return;
    int dir = t / N_PTS;
    int q   = t - dir * N_PTS;
    unsigned long long key = keys[dir * N_PTS + q];
    unsigned int hi = (unsigned int)(key >> 32);
    unsigned int lo = (unsigned int)(key & 0xFFFFFFFFu);
    unsigned int b  = (hi & 0x80000000u) ? (hi ^ 0x80000000u) : ~hi;  // inverse ordmap
    out[dir * N_PTS + q]       = __uint_as_float(b);   // dist1 | dist2
    out[(2 + dir) * N_PTS + q] = (float)lo;            // idx1  | idx2 (as float)
}

// ---- fallback (tiny workspace): direct kernel, correct but slow ----
__device__ __forceinline__ float np_pair(float sq, float sr,
                                         float qx, float qy, float qz,
                                         float rx, float ry, float rz) {
    float zz = __fadd_rn(__fadd_rn(__fmul_rn(qx, rx), __fmul_rn(qy, ry)),
                         __fmul_rn(qz, rz));
    return __fsub_rn(__fadd_rn(sq, sr), __fadd_rn(zz, zz));
}

__global__ __launch_bounds__(256) void chamfer_direct_kernel(
    const float* __restrict__ preds,
    const float* __restrict__ gts,
    float* __restrict__ out)
{
    __shared__ float4 spts[256];
    int bid = blockIdx.x;
    int dir = bid / QB79;
    int qb  = bid - dir * QB79;
    int q   = qb * 256 + threadIdx.x;

    const float* qpts = (dir == 0) ? preds : gts;
    const float* rpts = (dir == 0) ? gts   : preds;

    int qc = (q < N_PTS) ? q : (N_PTS - 1);
    float qx = qpts[qc * 3 + 0], qy = qpts[qc * 3 + 1], qz = qpts[qc * 3 + 2];
    float sq = np_self_dot(qx, qy, qz);
    float best = 3.4e38f;
    int   bidx = 0;

    for (int t = 0; t < N_PTS; t += 256) {
        int cnt = min(256, N_PTS - t);
        __syncthreads();
        if ((int)threadIdx.x < cnt) {
            int j = t + threadIdx.x;
            float rx = rpts[j * 3 + 0], ry = rpts[j * 3 + 1], rz = rpts[j * 3 + 2];
            spts[threadIdx.x] = make_float4(rx, ry, rz, np_self_dot(rx, ry, rz));
        }
        __syncthreads();
        for (int k = 0; k < cnt; ++k) {
            float4 r = spts[k];
            float d = np_pair(sq, r.w, qx, qy, qz, r.x, r.y, r.z);
            if (d < best) { best = d; bidx = t + k; }
        }
    }
    if (q < N_PTS) {
        out[dir * N_PTS + q]       = best;
        out[(2 + dir) * N_PTS + q] = (float)bidx;
    }
}

extern "C" void kernel_launch(void* const* d_in, const int* in_sizes, int n_in,
                              void* d_out, int out_size, void* d_ws, size_t ws_size,
                              hipStream_t stream) {
    const float* preds = (const float*)d_in[0];  // [20000, 3]
    const float* gts   = (const float*)d_in[1];  // [1, 20000, 3]
    float* out = (float*)d_out;

    size_t packed_bytes = (size_t)2 * N_PTS * sizeof(float4);              // 640 KB
    size_t keys_bytes   = (size_t)2 * N_PTS * sizeof(unsigned long long);  // 320 KB

    if (ws_size >= packed_bytes + keys_bytes) {
        float4* packed = (float4*)d_ws;
        unsigned long long* keys = (unsigned long long*)((char*)d_ws + packed_bytes);

        chamfer_prep<<<(2 * N_PTS + 255) / 256, 256, 0, stream>>>(preds, gts, packed, keys);
        chamfer_main<<<2 * NQB * NSEG, 256, 0, stream>>>(packed, keys);   // 1280 blocks
        chamfer_finalize<<<(2 * N_PTS + 255) / 256, 256, 0, stream>>>(keys, out);
    } else {
        chamfer_direct_kernel<<<2 * QB79, 256, 0, stream>>>(preds, gts, out);
    }
}